// Round 4
// baseline (207.064 us; speedup 1.0000x reference)
//
#include <hip/hip_runtime.h>
#include <stdint.h>

typedef _Float16 f16;
typedef _Float16 half8 __attribute__((ext_vector_type(8)));
typedef float f32x4 __attribute__((ext_vector_type(4)));

#define MFMA16(A, B, C) __builtin_amdgcn_mfma_f32_16x16x32_f16(A, B, C, 0, 0, 0)

#define GLOAD16(g, l) __builtin_amdgcn_global_load_lds( \
    (const __attribute__((address_space(1))) uint32_t*)(g), \
    (__attribute__((address_space(3))) uint32_t*)(l), 16, 0, 0)

__device__ inline void split2(float x, f16& h, f16& l) {
    h = (f16)x;
    l = (f16)(x - (float)h);
}

__device__ inline uint32_t packh(f16 a, f16 b) {
    union { f16 h[2]; uint32_t u; } t;
    t.h[0] = a; t.h[1] = b;
    return t.u;
}

// ---------------------------------------------------------------------------
// Fused conversion: x, Wqkv, Wproj -> f16 hi/lo splits, one launch.
// ---------------------------------------------------------------------------
#define XE4 786432
#define WQ4 110592
#define WP4 36864

__global__ void convert_all(const float* __restrict__ x,
                            const float* __restrict__ wq,
                            const float* __restrict__ wp,
                            f16* __restrict__ xh, f16* __restrict__ xl,
                            f16* __restrict__ wqh, f16* __restrict__ wql,
                            f16* __restrict__ wph, f16* __restrict__ wpl) {
    const int total = XE4 + WQ4 + WP4;
    for (int i = blockIdx.x * blockDim.x + threadIdx.x; i < total;
         i += gridDim.x * blockDim.x) {
        const float* src;
        f16 *hi, *lo;
        int idx = i;
        if (idx < XE4) { src = x; hi = xh; lo = xl; }
        else if (idx < XE4 + WQ4) { idx -= XE4; src = wq; hi = wqh; lo = wql; }
        else { idx -= XE4 + WQ4; src = wp; hi = wph; lo = wpl; }
        float4 v = ((const float4*)src)[idx];
        float vv[4] = {v.x, v.y, v.z, v.w};
        union { f16 x[4]; uint2 u; } H, L;
#pragma unroll
        for (int j = 0; j < 4; ++j) {
            f16 hh = (f16)vv[j];
            H.x[j] = hh;
            L.x[j] = (f16)(vv[j] - (float)hh);
        }
        ((uint2*)hi)[idx] = H.u;
        ((uint2*)lo)[idx] = L.u;
    }
}

// ---------------------------------------------------------------------------
// Kernel 1: qkv = x @ Wqkv^T. 128x128 tile, BK=32, double-buffered LDS,
// counted vmcnt. j-tiles 0..5 -> q/k (swapped operands, [bh][n][d] stores);
// j-tiles 6..8 -> v (normal operands, transposed [bh][d][n] stores).
// grid (64, 9), block 256.
// ---------------------------------------------------------------------------
__global__ __launch_bounds__(256) void qkv_gemm(
    const f16* __restrict__ xh, const f16* __restrict__ xl,
    const f16* __restrict__ wh, const f16* __restrict__ wl,
    f16* __restrict__ qh_, f16* __restrict__ ql_,
    f16* __restrict__ kh_, f16* __restrict__ kl_,
    f16* __restrict__ vth_, f16* __restrict__ vtl_) {
    __shared__ f16 sAh[2][4096], sAl[2][4096], sBh[2][4096], sBl[2][4096];
    const int tid = threadIdx.x;
    const int w = tid >> 6, lane = tid & 63;
    const int g = lane >> 4, q = lane & 15;
    const int m0 = blockIdx.x * 128, j0 = blockIdx.y * 128;
    const int wm = (w >> 1) * 64, wn = (w & 1) * 64;
    const bool isV = (j0 >= 768);

    const char* gb;
    if (w == 0)      gb = (const char*)xh + (size_t)m0 * 768;
    else if (w == 1) gb = (const char*)xl + (size_t)m0 * 768;
    else if (w == 2) gb = (const char*)wh + (size_t)j0 * 768;
    else             gb = (const char*)wl + (size_t)j0 * 768;

    auto STAGE = [&](int buf, int ks) {
        const char* gk = gb + ks * 64;
        f16* ld = (w == 0) ? sAh[buf] : (w == 1) ? sAl[buf]
                : (w == 2) ? sBh[buf] : sBl[buf];
#pragma unroll
        for (int i = 0; i < 8; ++i) {
            const int row = i * 16 + (lane >> 2);
            GLOAD16(gk + (size_t)row * 768 + (((lane & 3) ^ ((row & 6) >> 1)) << 4),
                    ld + i * 512);
        }
    };

    f32x4 acc[4][4];
#pragma unroll
    for (int i = 0; i < 4; ++i)
#pragma unroll
        for (int j = 0; j < 4; ++j) acc[i][j] = (f32x4){0.f, 0.f, 0.f, 0.f};

    asm volatile("" ::: "memory");
    STAGE(0, 0);
    int cur = 0;
    for (int ks = 0; ks < 12; ++ks) {
        __builtin_amdgcn_s_barrier();                 // prev compute done
        STAGE(cur ^ 1, (ks == 11) ? 0 : ks + 1);      // prefetch next
        asm volatile("s_waitcnt vmcnt(8)" ::: "memory"); // current tile landed
        __builtin_amdgcn_s_barrier();

        half8 am_h[4], am_l[4], bn_h[4], bn_l[4];
#pragma unroll
        for (int mi = 0; mi < 4; ++mi) {
            const int row = wm + 16 * mi + q;
            const int ch = (g ^ ((row & 6) >> 1)) * 8;
            am_h[mi] = *(const half8*)&sAh[cur][row * 32 + ch];
            am_l[mi] = *(const half8*)&sAl[cur][row * 32 + ch];
        }
#pragma unroll
        for (int nj = 0; nj < 4; ++nj) {
            const int row = wn + 16 * nj + q;
            const int ch = (g ^ ((row & 6) >> 1)) * 8;
            bn_h[nj] = *(const half8*)&sBh[cur][row * 32 + ch];
            bn_l[nj] = *(const half8*)&sBl[cur][row * 32 + ch];
        }
        if (!isV) {
#pragma unroll
            for (int mi = 0; mi < 4; ++mi)
#pragma unroll
                for (int nj = 0; nj < 4; ++nj) {
                    acc[mi][nj] = MFMA16(bn_h[nj], am_h[mi], acc[mi][nj]);
                    acc[mi][nj] = MFMA16(bn_l[nj], am_h[mi], acc[mi][nj]);
                    acc[mi][nj] = MFMA16(bn_h[nj], am_l[mi], acc[mi][nj]);
                }
        } else {
#pragma unroll
            for (int mi = 0; mi < 4; ++mi)
#pragma unroll
                for (int nj = 0; nj < 4; ++nj) {
                    acc[mi][nj] = MFMA16(am_h[mi], bn_h[nj], acc[mi][nj]);
                    acc[mi][nj] = MFMA16(am_h[mi], bn_l[nj], acc[mi][nj]);
                    acc[mi][nj] = MFMA16(am_l[mi], bn_h[nj], acc[mi][nj]);
                }
        }
        cur ^= 1;
    }

    if (!isV) {
        const int t = j0 / 384;
        const float sc = (t == 0) ? 0.125f : 1.0f;
        f16* dh = (t == 0) ? qh_ : kh_;
        f16* dl = (t == 0) ? ql_ : kl_;
#pragma unroll
        for (int nj = 0; nj < 4; ++nj) {
            const int jb = j0 + wn + 16 * nj + 4 * g;
            const int h = (jb - t * 384) >> 6, d0 = jb & 63;
#pragma unroll
            for (int mi = 0; mi < 4; ++mi) {
                const int mg = m0 + wm + 16 * mi + q;
                const int b = mg >> 10, n = mg & 1023;
                const size_t base = (size_t)(b * 6 + h) * 65536 + (size_t)n * 64 + d0;
                union { f16 x[4]; uint2 u; } H, L;
#pragma unroll
                for (int r = 0; r < 4; ++r)
                    split2(acc[mi][nj][r] * sc, H.x[r], L.x[r]);
                *(uint2*)&dh[base] = H.u;
                *(uint2*)&dl[base] = L.u;
            }
        }
    } else {
#pragma unroll
        for (int nj = 0; nj < 4; ++nj) {
            const int jc = j0 + wn + 16 * nj + q;
            const int h = (jc - 768) >> 6, d = jc & 63;
#pragma unroll
            for (int mi = 0; mi < 4; ++mi) {
                const int mg = m0 + wm + 16 * mi + 4 * g;
                const int b = mg >> 10, n = mg & 1023;
                const size_t bh = (size_t)(b * 6 + h);
                union { f16 x[4]; uint2 u; } HV, LV;
#pragma unroll
                for (int r = 0; r < 4; ++r) split2(acc[mi][nj][r], HV.x[r], LV.x[r]);
                *(uint2*)&vth_[bh * 65536 + (size_t)d * 1024 + n] = HV.u;
                *(uint2*)&vtl_[bh * 65536 + (size_t)d * 1024 + n] = LV.u;
            }
        }
    }
}

// ---------------------------------------------------------------------------
// Kernel 2: fused relu-attention. KVBLK=32, double-buffered (32KB LDS ->
// 3 blocks/CU, all 768 blocks co-resident). Split accumulator chains.
// grid 768 1D: bh = id%48 (XCD-local), qtile = id/48.
// ---------------------------------------------------------------------------
__global__ __launch_bounds__(256) void attn_mfma(
    const f16* __restrict__ qh_, const f16* __restrict__ ql_,
    const f16* __restrict__ kh_, const f16* __restrict__ kl_,
    const f16* __restrict__ vth_, const f16* __restrict__ vtl_,
    const float* __restrict__ alpha,
    f16* __restrict__ aoh, f16* __restrict__ aol) {
    __shared__ f16 sKh[2][2048], sKl[2][2048], sVh[2][2048], sVl[2][2048];
    const int tid = threadIdx.x;
    const int w = tid >> 6, lane = tid & 63;
    const int g = lane >> 4, q = lane & 15;
    const int bh = blockIdx.x % 48, h = bh % 6;
    const int n0 = (blockIdx.x / 48) * 64;

    const size_t kbb = (size_t)bh * 131072;   // byte offset of this bh

    auto STAGE = [&](int buf, int kt) {
        if (w < 2) {   // K tile: 32 rows x 64 d (128B rows)
            const f16* src = (w == 0) ? kh_ : kl_;
            f16* dst = (w == 0) ? sKh[buf] : sKl[buf];
            const size_t kb = kbb + (size_t)kt * 4096;
#pragma unroll
            for (int i = 0; i < 4; ++i) {
                const int rloc = i * 8 + (lane >> 3);
                GLOAD16((const char*)src + kb + (size_t)rloc * 128 +
                        (((lane & 7) ^ (rloc & 7)) << 4), dst + i * 512);
            }
        } else {       // V^T tile: 64 d-rows x 32 keys (64B rows)
            const f16* src = (w == 2) ? vth_ : vtl_;
            f16* dst = (w == 2) ? sVh[buf] : sVl[buf];
            const size_t vb = kbb + (size_t)kt * 64;
#pragma unroll
            for (int i = 0; i < 4; ++i) {
                const int rloc = i * 16 + (lane >> 2);
                GLOAD16((const char*)src + vb + (size_t)rloc * 2048 +
                        (((lane & 3) ^ (rloc & 3)) << 4), dst + i * 512);
            }
        }
    };

    // Q fragments + alpha pinned before staging (vmcnt bookkeeping)
    const size_t qbase = (size_t)bh * 65536 + (size_t)(n0 + 16 * w + q) * 64;
    half8 Qh[2], Ql[2];
    Qh[0] = *(const half8*)&qh_[qbase + g * 8];
    Qh[1] = *(const half8*)&qh_[qbase + 32 + g * 8];
    Ql[0] = *(const half8*)&ql_[qbase + g * 8];
    Ql[1] = *(const half8*)&ql_[qbase + 32 + g * 8];
    const float al = alpha[h];
    const float cg = (1.0f - al) * (1.0f / 1024.0f);
    const bool useLin = (cg != 0.0f);

    f32x4 accP[4], accP2[4], accS[4];
#pragma unroll
    for (int i = 0; i < 4; ++i) {
        accP[i] = (f32x4){0.f, 0.f, 0.f, 0.f};
        accP2[i] = (f32x4){0.f, 0.f, 0.f, 0.f};
        accS[i] = (f32x4){0.f, 0.f, 0.f, 0.f};
    }
    float rs = 0.f;

    asm volatile("" ::: "memory");
    STAGE(0, 0);
    int cur = 0;
    for (int kt = 0; kt < 32; ++kt) {
        __builtin_amdgcn_s_barrier();                 // prev compute done
        STAGE(cur ^ 1, (kt + 1) & 31);                // prefetch next tile
        asm volatile("s_waitcnt vmcnt(4)" ::: "memory");
        __builtin_amdgcn_s_barrier();                 // current tile ready

        // ---- S^T = K·Q^T, 3 split chains of depth 2
        f32x4 sa[2], sb[2], sc[2];
#pragma unroll
        for (int s = 0; s < 2; ++s) {
            sa[s] = (f32x4){0.f, 0.f, 0.f, 0.f};
            sb[s] = (f32x4){0.f, 0.f, 0.f, 0.f};
            sc[s] = (f32x4){0.f, 0.f, 0.f, 0.f};
            const int row = 16 * s + q;
#pragma unroll
            for (int k2 = 0; k2 < 2; ++k2) {
                const int ch = ((k2 * 4 + g) ^ (row & 7)) * 8;
                half8 kfh = *(const half8*)&sKh[cur][row * 64 + ch];
                half8 kfl = *(const half8*)&sKl[cur][row * 64 + ch];
                sa[s] = MFMA16(kfh, Qh[k2], sa[s]);
                sb[s] = MFMA16(kfh, Ql[k2], sb[s]);
                sc[s] = MFMA16(kfl, Qh[k2], sc[s]);
            }
        }
        f32x4 sv[2];
#pragma unroll
        for (int s = 0; s < 2; ++s) sv[s] = sa[s] + sb[s] + sc[s];

        // ---- relu + rowsum + split/pack
        uint32_t pkh[2][2], pkl[2][2];
#pragma unroll
        for (int s = 0; s < 2; ++s) {
            float p0 = fmaxf(sv[s][0], 0.f), p1 = fmaxf(sv[s][1], 0.f);
            float p2 = fmaxf(sv[s][2], 0.f), p3 = fmaxf(sv[s][3], 0.f);
            rs += (p0 + p1) + (p2 + p3);
            f16 h0, h1, h2, h3, l0, l1, l2, l3;
            split2(p0, h0, l0); split2(p1, h1, l1);
            split2(p2, h2, l2); split2(p3, h3, l3);
            pkh[s][0] = packh(h0, h1); pkh[s][1] = packh(h2, h3);
            pkl[s][0] = packh(l0, l1); pkl[s][1] = packh(l2, l3);
        }

        // ---- butterfly P redistribution + PV (split chains)
        {
            union { uint32_t u[4]; half8 v; } fh, fl;
#pragma unroll
            for (int r = 0; r < 4; ++r) {
                const int srcl = ((2 * g + (r >> 1)) & 3) * 16 + q;
                uint32_t a0 = __shfl(pkh[0][r & 1], srcl, 64);
                uint32_t b0 = __shfl(pkh[1][r & 1], srcl, 64);
                fh.u[r] = (g < 2) ? a0 : b0;
                uint32_t c0 = __shfl(pkl[0][r & 1], srcl, 64);
                uint32_t d0 = __shfl(pkl[1][r & 1], srcl, 64);
                fl.u[r] = (g < 2) ? c0 : d0;
            }
#pragma unroll
            for (int ds = 0; ds < 4; ++ds) {
                const int row = 16 * ds + q;
                const int ch = (g ^ (row & 3)) << 3;
                half8 vfh = *(const half8*)&sVh[cur][row * 32 + ch];
                half8 vfl = *(const half8*)&sVl[cur][row * 32 + ch];
                accP[ds]  = MFMA16(vfh, fh.v, accP[ds]);
                accP2[ds] = MFMA16(vfh, fl.v, accP2[ds]);
                accP2[ds] = MFMA16(vfl, fh.v, accP2[ds]);
            }
        }

        if (useLin) {
            uint32_t skh[2][2], skl[2][2];
#pragma unroll
            for (int s = 0; s < 2; ++s) {
                f16 h0, h1, h2, h3, l0, l1, l2, l3;
                split2(sv[s][0], h0, l0); split2(sv[s][1], h1, l1);
                split2(sv[s][2], h2, l2); split2(sv[s][3], h3, l3);
                skh[s][0] = packh(h0, h1); skh[s][1] = packh(h2, h3);
                skl[s][0] = packh(l0, l1); skl[s][1] = packh(l2, l3);
            }
            union { uint32_t u[4]; half8 v; } fh, fl;
#pragma unroll
            for (int r = 0; r < 4; ++r) {
                const int srcl = ((2 * g + (r >> 1)) & 3) * 16 + q;
                uint32_t a0 = __shfl(skh[0][r & 1], srcl, 64);
                uint32_t b0 = __shfl(skh[1][r & 1], srcl, 64);
                fh.u[r] = (g < 2) ? a0 : b0;
                uint32_t c0 = __shfl(skl[0][r & 1], srcl, 64);
                uint32_t d0 = __shfl(skl[1][r & 1], srcl, 64);
                fl.u[r] = (g < 2) ? c0 : d0;
            }
#pragma unroll
            for (int ds = 0; ds < 4; ++ds) {
                const int row = 16 * ds + q;
                const int ch = (g ^ (row & 3)) << 3;
                half8 vfh = *(const half8*)&sVh[cur][row * 32 + ch];
                half8 vfl = *(const half8*)&sVl[cur][row * 32 + ch];
                accS[ds] = MFMA16(vfh, fh.v, accS[ds]);
                accS[ds] = MFMA16(vfh, fl.v, accS[ds]);
                accS[ds] = MFMA16(vfl, fh.v, accS[ds]);
            }
        }
        cur ^= 1;
    }

    rs += __shfl_xor(rs, 16, 64);
    rs += __shfl_xor(rs, 32, 64);
    const float inv = al / (rs + 1e-5f);

    const int b = bh / 6;
    const size_t arow = (size_t)(b * 1024 + n0 + 16 * w + q) * 384 + h * 64;
#pragma unroll
    for (int ds = 0; ds < 4; ++ds) {
        const int d0 = 16 * ds + 4 * g;
        union { f16 x[4]; uint2 u; } H, L;
#pragma unroll
        for (int r = 0; r < 4; ++r) {
            float v = (accP[ds][r] + accP2[ds][r]) * inv + cg * accS[ds][r];
            split2(v, H.x[r], L.x[r]);
        }
        *(uint2*)&aoh[arow + d0] = H.u;
        *(uint2*)&aol[arow + d0] = L.u;
    }
}

// ---------------------------------------------------------------------------
// Kernel 3: out = aout @ Wproj^T + bias. 64x128 tile, double-buffered.
// grid (128, 3), block 256.
// ---------------------------------------------------------------------------
__global__ __launch_bounds__(256) void proj_gemm(
    const f16* __restrict__ ah_, const f16* __restrict__ al_,
    const f16* __restrict__ wh, const f16* __restrict__ wl,
    const float* __restrict__ bias, float* __restrict__ out) {
    __shared__ f16 sAh[2][2048], sAl[2][2048], sBh[2][4096], sBl[2][4096];
    const int tid = threadIdx.x;
    const int w = tid >> 6, lane = tid & 63;
    const int g = lane >> 4, q = lane & 15;
    const int m0 = blockIdx.x * 64, j0 = blockIdx.y * 128;
    const int wm = (w >> 1) * 32, wn = (w & 1) * 64;

    auto STAGE = [&](int buf, int ks) {
        if (w < 2) {
            const char* gb = (const char*)(w == 0 ? ah_ : al_) + (size_t)m0 * 768 + ks * 64;
            f16* ld = (w == 0) ? sAh[buf] : sAl[buf];
#pragma unroll
            for (int i = 0; i < 4; ++i) {
                const int row = i * 16 + (lane >> 2);
                GLOAD16(gb + (size_t)row * 768 + (((lane & 3) ^ ((row & 6) >> 1)) << 4),
                        ld + i * 512);
            }
        } else {
            const char* gb = (const char*)(w == 2 ? wh : wl) + (size_t)j0 * 768 + ks * 64;
            f16* ld = (w == 2) ? sBh[buf] : sBl[buf];
#pragma unroll
            for (int i = 0; i < 8; ++i) {
                const int row = i * 16 + (lane >> 2);
                GLOAD16(gb + (size_t)row * 768 + (((lane & 3) ^ ((row & 6) >> 1)) << 4),
                        ld + i * 512);
            }
        }
    };

    f32x4 acc[2][4];
#pragma unroll
    for (int i = 0; i < 2; ++i)
#pragma unroll
        for (int j = 0; j < 4; ++j) acc[i][j] = (f32x4){0.f, 0.f, 0.f, 0.f};

    asm volatile("" ::: "memory");
    STAGE(0, 0);
    int cur = 0;
    for (int ks = 0; ks < 12; ++ks) {
        __builtin_amdgcn_s_barrier();
        STAGE(cur ^ 1, (ks == 11) ? 0 : ks + 1);
        if (w < 2) asm volatile("s_waitcnt vmcnt(4)" ::: "memory");
        else       asm volatile("s_waitcnt vmcnt(8)" ::: "memory");
        __builtin_amdgcn_s_barrier();

        half8 am_h[2], am_l[2], bn_h[4], bn_l[4];
#pragma unroll
        for (int mi = 0; mi < 2; ++mi) {
            const int row = wm + 16 * mi + q;
            const int ch = (g ^ ((row & 6) >> 1)) * 8;
            am_h[mi] = *(const half8*)&sAh[cur][row * 32 + ch];
            am_l[mi] = *(const half8*)&sAl[cur][row * 32 + ch];
        }
#pragma unroll
        for (int nj = 0; nj < 4; ++nj) {
            const int row = wn + 16 * nj + q;
            const int ch = (g ^ ((row & 6) >> 1)) * 8;
            bn_h[nj] = *(const half8*)&sBh[cur][row * 32 + ch];
            bn_l[nj] = *(const half8*)&sBl[cur][row * 32 + ch];
        }
#pragma unroll
        for (int mi = 0; mi < 2; ++mi)
#pragma unroll
            for (int nj = 0; nj < 4; ++nj) {
                acc[mi][nj] = MFMA16(bn_h[nj], am_h[mi], acc[mi][nj]);
                acc[mi][nj] = MFMA16(bn_l[nj], am_h[mi], acc[mi][nj]);
                acc[mi][nj] = MFMA16(bn_h[nj], am_l[mi], acc[mi][nj]);
            }
        cur ^= 1;
    }

#pragma unroll
    for (int nj = 0; nj < 4; ++nj) {
        const int jb = j0 + wn + 16 * nj + 4 * g;
        const float4 bb = *(const float4*)&bias[jb];
#pragma unroll
        for (int mi = 0; mi < 2; ++mi) {
            const int m = m0 + wm + 16 * mi + q;
            float4 o;
            o.x = acc[mi][nj][0] + bb.x;
            o.y = acc[mi][nj][1] + bb.y;
            o.z = acc[mi][nj][2] + bb.z;
            o.w = acc[mi][nj][3] + bb.w;
            *(float4*)&out[(size_t)m * 384 + jb] = o;
        }
    }
}

// ---------------------------------------------------------------------------
extern "C" void kernel_launch(void* const* d_in, const int* in_sizes, int n_in,
                              void* d_out, int out_size, void* d_ws, size_t ws_size,
                              hipStream_t stream) {
    const float* x     = (const float*)d_in[0];
    const float* Wqkv  = (const float*)d_in[1];
    const float* Wproj = (const float*)d_in[2];
    const float* bproj = (const float*)d_in[3];
    const float* alpha = (const float*)d_in[4];
    float* out = (float*)d_out;

    f16* ws = (f16*)d_ws;
    const size_t XE = 8192 * 384;
    const size_t WQ = 1152 * 384;
    const size_t WP = 384 * 384;
    const size_t QE = 48 * 1024 * 64;

    f16* xh  = ws;            f16* xl  = xh + XE;
    f16* wqh = xl + XE;       f16* wql = wqh + WQ;
    f16* wph = wql + WQ;      f16* wpl = wph + WP;
    f16* qh  = wpl + WP;      f16* ql  = qh + QE;
    f16* kh  = ql + QE;       f16* kl  = kh + QE;
    f16* vth = kl + QE;       f16* vtl = vth + QE;
    f16* aoh = vtl + QE;      f16* aol = aoh + XE;

    convert_all<<<1024, 256, 0, stream>>>(x, Wqkv, Wproj, xh, xl,
                                          wqh, wql, wph, wpl);
    qkv_gemm<<<dim3(64, 9), 256, 0, stream>>>(xh, xl, wqh, wql,
                                              qh, ql, kh, kl, vth, vtl);
    attn_mfma<<<768, 256, 0, stream>>>(qh, ql, kh, kl, vth, vtl,
                                       alpha, aoh, aol);
    proj_gemm<<<dim3(128, 3), 256, 0, stream>>>(aoh, aol, wph, wpl, bproj, out);
}